// Round 3
// baseline (254.678 us; speedup 1.0000x reference)
//
#include <hip/hip_runtime.h>
#include <hip/hip_bf16.h>
#include <stdint.h>

// B=8, n=64, C=32, O=32
#define NC   2048      // n*C
#define NNC  131072    // n*n*C
#define N3C  8388608   // n*n*n*C per batch
#define CMPE 1048576   // per-comp elements (B*n*n*C)

typedef unsigned short u16;

__device__ __forceinline__ u16 bf16b(float x){
    unsigned u = __float_as_uint(x);
    u += 0x7FFFu + ((u >> 16) & 1u);      // RNE
    return (u16)(u >> 16);
}
__device__ __forceinline__ float b2f(u16 h){ return __uint_as_float(((unsigned)h) << 16); }
__device__ __forceinline__ float lo16(unsigned u){ return __uint_as_float(u << 16); }
__device__ __forceinline__ float hi16(unsigned u){ return __uint_as_float(u & 0xFFFF0000u); }
__device__ __forceinline__ void f4acc(float4& a, const float4 b){
    a.x += b.x; a.y += b.y; a.z += b.z; a.w += b.w;
}
__device__ __forceinline__ uint2 pack4(float4 v){
    uint2 r;
    r.x = (unsigned)bf16b(v.x) | ((unsigned)bf16b(v.y) << 16);
    r.y = (unsigned)bf16b(v.z) | ((unsigned)bf16b(v.w) << 16);
    return r;
}
__device__ __forceinline__ uint2 pack4s(float4 v, float s){
    v.x *= s; v.y *= s; v.z *= s; v.w *= s;
    return pack4(v);
}

// ---------------------------------------------------------------------------
// K1: single pass over x. Block=(b, ig, jg): i in [8ig,8ig+8), j in [8jg,8jg+8).
// Emits p1[b][ig][j][kc] (fp32 partial sum_i), p2[b][jg][i][kc] (partial sum_j),
// s3 comp (mean_k) bf16, d12/d13/d23 comps bf16 (raw diagonals).
__global__ __launch_bounds__(256, 2) void k_pass1(
    const float* __restrict__ x,
    float* __restrict__ p1, float* __restrict__ p2,
    u16* __restrict__ c_s3, u16* __restrict__ c_d12,
    u16* __restrict__ c_d13, u16* __restrict__ c_d23)
{
    int blk = blockIdx.x;                 // (b*8+ig)*8+jg
    int jg = blk & 7, ig = (blk >> 3) & 7, b = blk >> 6;
    int t = threadIdx.x;
    int kt = t >> 3, c4 = (t & 7) * 4;

    __shared__ float s3l[8][8][32];
    #pragma unroll
    for (int r = 0; r < 8; ++r) (&s3l[0][0][0])[t + r * 256] = 0.f;
    __syncthreads();

    float4 p1a[8][2];
    #pragma unroll
    for (int a = 0; a < 8; ++a){
        p1a[a][0] = make_float4(0,0,0,0);
        p1a[a][1] = make_float4(0,0,0,0);
    }

    const float* xb = x + (size_t)b * N3C + (size_t)ig * 8 * NNC + (size_t)jg * 8 * NC;

    for (int ii = 0; ii < 8; ++ii){
        int i = ig * 8 + ii;
        float4 q0 = make_float4(0,0,0,0), q1 = make_float4(0,0,0,0);  // p2 row acc
        #pragma unroll
        for (int jj = 0; jj < 8; ++jj){
            int j = jg * 8 + jj;
            const float* row = xb + (size_t)ii * NNC + (size_t)jj * NC;
            float4 v0 = *reinterpret_cast<const float4*>(row + 4 * t);
            float4 v1 = *reinterpret_cast<const float4*>(row + 1024 + 4 * t);
            f4acc(p1a[jj][0], v0); f4acc(p1a[jj][1], v1);
            f4acc(q0, v0);         f4acc(q1, v1);
            float4 s; s.x = v0.x + v1.x; s.y = v0.y + v1.y;
            s.z = v0.z + v1.z; s.w = v0.w + v1.w;
            atomicAdd(&s3l[ii][jj][c4 + 0], s.x);
            atomicAdd(&s3l[ii][jj][c4 + 1], s.y);
            atomicAdd(&s3l[ii][jj][c4 + 2], s.z);
            atomicAdd(&s3l[ii][jj][c4 + 3], s.w);
            // d13[b,i,j,c] = x[b,i,j,k=i,c]
            if (kt == (i & 31)){
                uint2 d = pack4((i < 32) ? v0 : v1);
                *reinterpret_cast<uint2*>(c_d13 + (((size_t)(b * 64 + i)) * 64 + j) * 32 + c4) = d;
            }
            // d23[b,i,j,c] = x[b,i,j,k=j,c]
            if (kt == (j & 31)){
                uint2 d = pack4((j < 32) ? v0 : v1);
                *reinterpret_cast<uint2*>(c_d23 + (((size_t)(b * 64 + i)) * 64 + j) * 32 + c4) = d;
            }
            // d12[b,i,k,c] = x[b,i,i,k,c]
            if (i == j){
                *reinterpret_cast<uint2*>(c_d12 + ((size_t)(b * 64 + i)) * 2048 + 4 * t)        = pack4(v0);
                *reinterpret_cast<uint2*>(c_d12 + ((size_t)(b * 64 + i)) * 2048 + 1024 + 4 * t) = pack4(v1);
            }
        }
        float* o2 = p2 + ((size_t)((b * 8 + jg) * 64 + i)) * 2048;
        *reinterpret_cast<float4*>(o2 + 4 * t)        = q0;
        *reinterpret_cast<float4*>(o2 + 1024 + 4 * t) = q1;
    }
    #pragma unroll
    for (int jj = 0; jj < 8; ++jj){
        float* o1 = p1 + ((size_t)((b * 8 + ig) * 64 + jg * 8 + jj)) * 2048;
        *reinterpret_cast<float4*>(o1 + 4 * t)        = p1a[jj][0];
        *reinterpret_cast<float4*>(o1 + 1024 + 4 * t) = p1a[jj][1];
    }
    __syncthreads();
    {   // s3 comp write: mean over k
        int ii = t >> 5, jj = (t >> 2) & 7, c8 = (t & 3) * 8;
        int i = ig * 8 + ii, j = jg * 8 + jj;
        const float* sp = &s3l[ii][jj][c8];
        float4 u0 = make_float4(sp[0], sp[1], sp[2], sp[3]);
        float4 u1 = make_float4(sp[4], sp[5], sp[6], sp[7]);
        uint2 w0 = pack4s(u0, 1.f/64.f), w1 = pack4s(u1, 1.f/64.f);
        uint4 o; o.x = w0.x; o.y = w0.y; o.z = w1.x; o.w = w1.y;
        *reinterpret_cast<uint4*>(c_s3 + (((size_t)(b * 64 + i)) * 64 + j) * 32 + c8) = o;
    }
}

// ---------------------------------------------------------------------------
// K2: reduce 8 partials -> s1/s2 comps (bf16 means). 512 blocks.
__global__ __launch_bounds__(256) void k_reduce(
    const float* __restrict__ p1, const float* __restrict__ p2,
    u16* __restrict__ c_s1, u16* __restrict__ c_s2)
{
    int blk = blockIdx.x;                 // b*64 + sx*32 + ch
    int b = blk >> 6, sx = (blk >> 5) & 1, ch = blk & 31;
    const float* P = sx ? p2 : p1;
    u16* O = sx ? c_s2 : c_s1;
    int t = threadIdx.x;
    #pragma unroll
    for (int r2 = 0; r2 < 2; ++r2){
        int row = ch * 2 + r2;
        float4 a0v = make_float4(0,0,0,0), a1v = make_float4(0,0,0,0);
        #pragma unroll
        for (int g = 0; g < 8; ++g){
            const float* src = P + ((size_t)((b * 8 + g) * 64 + row)) * 2048;
            f4acc(a0v, *reinterpret_cast<const float4*>(src + 4 * t));
            f4acc(a1v, *reinterpret_cast<const float4*>(src + 1024 + 4 * t));
        }
        u16* ob = O + ((size_t)(b * 64 + row)) * 2048;
        *reinterpret_cast<uint2*>(ob + 4 * t)        = pack4s(a0v, 1.f/64.f);
        *reinterpret_cast<uint2*>(ob + 1024 + 4 * t) = pack4s(a1v, 1.f/64.f);
    }
}

// ---------------------------------------------------------------------------
// K3: a1 [B][64][320], a0 [B][160] from bf16 comps. Block=(b, m, pchunk16).
__global__ __launch_bounds__(256) void k_a1a0(
    const u16* __restrict__ comps,
    float* __restrict__ a1, float* __restrict__ a0)
{
    int blk = blockIdx.x;                 // 160: (b*5+m)*4 + pc
    int pc = blk & 3, m = (blk >> 2) % 5, b = blk / 20;
    const int cidx [5] = {0, 1, 3, 4, 5};
    const int rowch[5] = {1, 2, 4, 6, 8};
    const int colch[5] = {0, -1, 3, 5, 7};
    const int a0i  [5] = {0, -1, 1, 2, 3};

    const u16* M = comps + (size_t)cidx[m] * CMPE + (size_t)b * NNC;
    int t = threadIdx.x, c = t & 31, qb = (t >> 5) * 8;
    int p0 = pc * 16;
    float colacc[8] = {0,0,0,0,0,0,0,0};
    __shared__ float red[2048];
    __shared__ float rowc[16][32];
    for (int pp0 = 0; pp0 < 16; pp0 += 8){
        #pragma unroll
        for (int pp = 0; pp < 8; ++pp){
            const u16* row = M + (size_t)(p0 + pp0 + pp) * 2048;
            float part = 0.f;
            #pragma unroll
            for (int kk = 0; kk < 8; ++kk){
                float v = b2f(row[(qb + kk) * 32 + c]);
                colacc[kk] += v; part += v;
            }
            red[pp * 256 + t] = part;
        }
        __syncthreads();
        {
            int pp = t >> 5, cc = t & 31;
            float ssum = 0.f;
            #pragma unroll
            for (int g = 0; g < 8; ++g) ssum += red[pp * 256 + g * 32 + cc];
            rowc[pp0 + pp][cc] = ssum;
            a1[((size_t)b * 64 + p0 + pp0 + pp) * 320 + rowch[m] * 32 + cc] = ssum * (1.f/64.f);
        }
        __syncthreads();
    }
    if (colch[m] >= 0){
        #pragma unroll
        for (int kk = 0; kk < 8; ++kk)
            atomicAdd(&a1[((size_t)b * 64 + qb + kk) * 320 + colch[m] * 32 + c],
                      colacc[kk] * (1.f/64.f));
    }
    if (a0i[m] >= 0 && t < 32){
        float tot = 0.f;
        #pragma unroll
        for (int r = 0; r < 16; ++r) tot += rowc[r][t];
        atomicAdd(&a0[(size_t)b * 160 + a0i[m] * 32 + t], tot * (1.f/4096.f));
    }
    if (m == 2){                          // d12 triple-diag -> chunk9 + a0[4]
        #pragma unroll
        for (int r = 0; r < 2; ++r){
            int idx = t + r * 256;        // 0..511
            int pl = idx >> 5, cc = idx & 31;
            int p = p0 + pl;
            float dv = b2f(M[((size_t)p * 64 + p) * 32 + cc]);
            a1[((size_t)b * 64 + p) * 320 + 288 + cc] = dv;
            atomicAdd(&a0[(size_t)b * 160 + 128 + cc], dv * (1.f/64.f));
        }
    }
}

// ---------------------------------------------------------------------------
// K4: u1p/u1t/fov vectors from a1,a0.
__global__ __launch_bounds__(256) void k_uvec(
    const float* __restrict__ a1, const float* __restrict__ a0,
    float* __restrict__ u1p, float* __restrict__ u1t, float* __restrict__ fov,
    const float* __restrict__ W12,  const float* __restrict__ b12,
    const float* __restrict__ W12t, const float* __restrict__ b12t,
    const float* __restrict__ W02,  const float* __restrict__ b02,
    const float* __restrict__ W11,  const float* __restrict__ b11,
    const float* __restrict__ W01,  const float* __restrict__ b01,
    const float* __restrict__ b22)
{
    int b = blockIdx.x >> 3, pg = blockIdx.x & 7;   // 64 blocks
    int t = threadIdx.x;
    int p = pg * 8 + (t >> 5), o = t & 31;
    const float* a1r = a1 + ((size_t)b * 64 + p) * 320;
    const float* a0r = a0 + (size_t)b * 160;
    float accP = b12[o] + b02[o] + b22[o];
    float accT = b12t[o];
    float accF = b11[o] + b01[o];
    for (int f = 0; f < 320; ++f){
        float a = a1r[f];
        accP = fmaf(a, W12 [f * 32 + o], accP);
        accT = fmaf(a, W12t[f * 32 + o], accT);
        accF = fmaf(a, W11 [f * 32 + o], accF);
    }
    for (int g = 0; g < 160; ++g){
        float a = a0r[g];
        accP = fmaf(a, W02[g * 32 + o], accP);
        accF = fmaf(a, W01[g * 32 + o], accF);
    }
    size_t idx = ((size_t)b * 64 + p) * 32 + o;
    u1p[idx] = accP; u1t[idx] = accT; fov[idx] = accF;
}

// ---------------------------------------------------------------------------
// K5: out[b,p,q,o] = A[q,f]@W22[f,o] + B[q,f]@W22[192+f,o] + u1p[b,p,o]
//                    + u1t[b,q,o] + (p==q)*fov[b,p,o]
__global__ __launch_bounds__(256, 2) void k_out(
    const u16* __restrict__ comps, const float* __restrict__ W22,
    const float* __restrict__ u1p, const float* __restrict__ u1t,
    const float* __restrict__ fov, float* __restrict__ out)
{
    __shared__ __align__(16) u16 Ast[192 * 68];   // [f][q], pad 68
    __shared__ __align__(16) u16 Bst[192 * 68];
    __shared__ __align__(16) u16 Wls[192 * 32];   // [f][o]
    int blk = blockIdx.x;                 // b*64+p
    int b = blk >> 6, p = blk & 63;
    int t = threadIdx.x;
    int q = t >> 2, c8 = (t & 3) * 8;

    #pragma unroll
    for (int t6 = 0; t6 < 6; ++t6){
        const u16* cmp = comps + (size_t)t6 * CMPE + (size_t)b * NNC;
        uint4 av = *reinterpret_cast<const uint4*>(cmp + (size_t)p * 2048 + q * 32 + c8);
        uint4 bv = *reinterpret_cast<const uint4*>(cmp + (size_t)q * 2048 + p * 32 + c8);
        int fb = t6 * 32 + c8;
        Ast[(fb+0)*68 + q] = (u16)av.x; Ast[(fb+1)*68 + q] = (u16)(av.x >> 16);
        Ast[(fb+2)*68 + q] = (u16)av.y; Ast[(fb+3)*68 + q] = (u16)(av.y >> 16);
        Ast[(fb+4)*68 + q] = (u16)av.z; Ast[(fb+5)*68 + q] = (u16)(av.z >> 16);
        Ast[(fb+6)*68 + q] = (u16)av.w; Ast[(fb+7)*68 + q] = (u16)(av.w >> 16);
        Bst[(fb+0)*68 + q] = (u16)bv.x; Bst[(fb+1)*68 + q] = (u16)(bv.x >> 16);
        Bst[(fb+2)*68 + q] = (u16)bv.y; Bst[(fb+3)*68 + q] = (u16)(bv.y >> 16);
        Bst[(fb+4)*68 + q] = (u16)bv.z; Bst[(fb+5)*68 + q] = (u16)(bv.z >> 16);
        Bst[(fb+6)*68 + q] = (u16)bv.w; Bst[(fb+7)*68 + q] = (u16)(bv.w >> 16);
    }
    #pragma unroll
    for (int r = 0; r < 6; ++r){          // W half 0
        int idx = t + r * 256;
        int f = idx >> 3, o4 = (idx & 7) * 4;
        float4 w = *reinterpret_cast<const float4*>(W22 + (size_t)idx * 4);
        Wls[f*32 + o4 + 0] = bf16b(w.x); Wls[f*32 + o4 + 1] = bf16b(w.y);
        Wls[f*32 + o4 + 2] = bf16b(w.z); Wls[f*32 + o4 + 3] = bf16b(w.w);
    }
    __syncthreads();

    int qi = t & 15, oi = t >> 4;
    int q0 = qi * 4, o0 = oi * 2;
    float acc00=0,acc01=0,acc10=0,acc11=0,acc20=0,acc21=0,acc30=0,acc31=0;

    #pragma unroll 8
    for (int f = 0; f < 192; ++f){
        uint2 a4 = *reinterpret_cast<const uint2*>(Ast + f * 68 + q0);
        unsigned wp = *reinterpret_cast<const unsigned*>(Wls + f * 32 + o0);
        float w0v = lo16(wp), w1v = hi16(wp);
        float A0v = lo16(a4.x), A1v = hi16(a4.x), A2v = lo16(a4.y), A3v = hi16(a4.y);
        acc00 = fmaf(A0v, w0v, acc00); acc01 = fmaf(A0v, w1v, acc01);
        acc10 = fmaf(A1v, w0v, acc10); acc11 = fmaf(A1v, w1v, acc11);
        acc20 = fmaf(A2v, w0v, acc20); acc21 = fmaf(A2v, w1v, acc21);
        acc30 = fmaf(A3v, w0v, acc30); acc31 = fmaf(A3v, w1v, acc31);
    }
    __syncthreads();
    #pragma unroll
    for (int r = 0; r < 6; ++r){          // W half 1
        int idx = t + r * 256;
        int f = idx >> 3, o4 = (idx & 7) * 4;
        float4 w = *reinterpret_cast<const float4*>(W22 + 6144 + (size_t)idx * 4);
        Wls[f*32 + o4 + 0] = bf16b(w.x); Wls[f*32 + o4 + 1] = bf16b(w.y);
        Wls[f*32 + o4 + 2] = bf16b(w.z); Wls[f*32 + o4 + 3] = bf16b(w.w);
    }
    __syncthreads();
    #pragma unroll 8
    for (int f = 0; f < 192; ++f){
        uint2 a4 = *reinterpret_cast<const uint2*>(Bst + f * 68 + q0);
        unsigned wp = *reinterpret_cast<const unsigned*>(Wls + f * 32 + o0);
        float w0v = lo16(wp), w1v = hi16(wp);
        float A0v = lo16(a4.x), A1v = hi16(a4.x), A2v = lo16(a4.y), A3v = hi16(a4.y);
        acc00 = fmaf(A0v, w0v, acc00); acc01 = fmaf(A0v, w1v, acc01);
        acc10 = fmaf(A1v, w0v, acc10); acc11 = fmaf(A1v, w1v, acc11);
        acc20 = fmaf(A2v, w0v, acc20); acc21 = fmaf(A2v, w1v, acc21);
        acc30 = fmaf(A3v, w0v, acc30); acc31 = fmaf(A3v, w1v, acc31);
    }

    size_t ub = ((size_t)b * 64 + p) * 32;
    float up0 = u1p[ub + o0], up1 = u1p[ub + o0 + 1];
    const float* fovp = fov + ub;
    float accs[4][2] = {{acc00,acc01},{acc10,acc11},{acc20,acc21},{acc30,acc31}};
    #pragma unroll
    for (int iq = 0; iq < 4; ++iq){
        int qq = q0 + iq;
        size_t tb = ((size_t)b * 64 + qq) * 32;
        float e0 = up0 + u1t[tb + o0];
        float e1 = up1 + u1t[tb + o0 + 1];
        if (qq == p){ e0 += fovp[o0]; e1 += fovp[o0 + 1]; }
        float2 v; v.x = accs[iq][0] + e0; v.y = accs[iq][1] + e1;
        *reinterpret_cast<float2*>(out + (((size_t)b * 64 + p) * 64 + qq) * 32 + o0) = v;
    }
}

// ---------------------------------------------------------------------------
extern "C" void kernel_launch(void* const* d_in, const int* in_sizes, int n_in,
                              void* d_out, int out_size, void* d_ws, size_t ws_size,
                              hipStream_t stream){
    const float* x    = (const float*)d_in[0];
    const float* W22  = (const float*)d_in[1];
    const float* b22  = (const float*)d_in[2];
    const float* W12  = (const float*)d_in[3];
    const float* b12  = (const float*)d_in[4];
    const float* W12t = (const float*)d_in[5];
    const float* b12t = (const float*)d_in[6];
    const float* W02  = (const float*)d_in[7];
    const float* b02  = (const float*)d_in[8];
    const float* W11  = (const float*)d_in[9];
    const float* b11  = (const float*)d_in[10];
    const float* W01  = (const float*)d_in[11];
    const float* b01  = (const float*)d_in[12];
    float* out = (float*)d_out;
    float* ws  = (float*)d_ws;

    // ws layout (float offsets) — p1/p2 are [B][8][64][2048] = 8,388,608 floats EACH
    float* p1   = ws;                        // [0, 8388608)
    float* p2   = ws + 8388608;              // [8388608, 16777216)
    u16*  comps = (u16*)(ws + 16777216);     // 6*CMPE u16 = 3,145,728 float-slots
    float* a1   = ws + 19922944;             // 163,840 f
    float* a0   = ws + 20086784;             // 1,280 f
    float* u1p  = ws + 20088064;             // 16,384 f
    float* u1t  = ws + 20104448;             // 16,384 f
    float* fovv = ws + 20120832;             // 16,384 f

    hipMemsetAsync(a1, 0, (163840 + 1280) * sizeof(float), stream);
    k_pass1 <<<512, 256, 0, stream>>>(x, p1, p2,
                comps + 2*(size_t)CMPE, comps + 3*(size_t)CMPE,
                comps + 4*(size_t)CMPE, comps + 5*(size_t)CMPE);
    k_reduce<<<512, 256, 0, stream>>>(p1, p2, comps, comps + (size_t)CMPE);
    k_a1a0  <<<160, 256, 0, stream>>>(comps, a1, a0);
    k_uvec  <<<64,  256, 0, stream>>>(a1, a0, u1p, u1t, fovv,
                W12, b12, W12t, b12t, W02, b02, W11, b11, W01, b01, b22);
    k_out   <<<512, 256, 0, stream>>>(comps, W22, u1p, u1t, fovv, out);
}

// Round 5
// 156.453 us; speedup vs baseline: 1.6278x; 1.6278x over previous
//
#include <hip/hip_runtime.h>
#include <hip/hip_bf16.h>
#include <stdint.h>

// B=8, n=64, C=32, O=32
#define NC   2048      // n*C
#define NNC  131072    // n*n*C
#define N3C  8388608   // n*n*n*C per batch
#define CMPE 1048576   // per-comp elements (B*n*n*C)

typedef unsigned short u16;

__device__ __forceinline__ u16 bf16b(float x){
    unsigned u = __float_as_uint(x);
    u += 0x7FFFu + ((u >> 16) & 1u);      // RNE
    return (u16)(u >> 16);
}
__device__ __forceinline__ float b2f(u16 h){ return __uint_as_float(((unsigned)h) << 16); }
__device__ __forceinline__ float lo16(unsigned u){ return __uint_as_float(u << 16); }
__device__ __forceinline__ float hi16(unsigned u){ return __uint_as_float(u & 0xFFFF0000u); }
__device__ __forceinline__ void f4acc(float4& a, const float4 b){
    a.x += b.x; a.y += b.y; a.z += b.z; a.w += b.w;
}
__device__ __forceinline__ uint2 pack4(float4 v){
    uint2 r;
    r.x = (unsigned)bf16b(v.x) | ((unsigned)bf16b(v.y) << 16);
    r.y = (unsigned)bf16b(v.z) | ((unsigned)bf16b(v.w) << 16);
    return r;
}
__device__ __forceinline__ uint2 pack4s(float4 v, float s){
    v.x *= s; v.y *= s; v.z *= s; v.w *= s;
    return pack4(v);
}

// ---------------------------------------------------------------------------
// K1: single pass over x. Block=(b, ig, jg), 512 threads: thread=(k, c4).
// No atomics: s3's k-reduction via private-slot LDS transpose, 2 syncs/ii.
__global__ __launch_bounds__(512, 4) void k_pass1(
    const float* __restrict__ x,
    float* __restrict__ p1, float* __restrict__ p2,
    u16* __restrict__ c_s3, u16* __restrict__ c_d12,
    u16* __restrict__ c_d13, u16* __restrict__ c_d23)
{
    int blk = blockIdx.x;                 // (b*8+ig)*8+jg
    int jg = blk & 7, ig = (blk >> 3) & 7, b = blk >> 6;
    int t = threadIdx.x;                  // 0..511
    int kt = t >> 3, c4 = (t & 7) * 4;    // k 0..63, c4 in {0,4,...,28}

    __shared__ float s3l[8][32][65];      // [jj][c][kt pad65]  66.6 KB

    float4 p1a[8];
    #pragma unroll
    for (int a = 0; a < 8; ++a) p1a[a] = make_float4(0,0,0,0);

    const float* xb = x + (size_t)b * N3C + (size_t)ig * 8 * NNC + (size_t)jg * 8 * NC;

    int rjj = t >> 6, rh = (t >> 5) & 1, rc = t & 31;   // reduce mapping

    for (int ii = 0; ii < 8; ++ii){
        int i = ig * 8 + ii;
        float4 q = make_float4(0,0,0,0);
        #pragma unroll
        for (int jj = 0; jj < 8; ++jj){
            int j = jg * 8 + jj;
            const float* row = xb + (size_t)ii * NNC + (size_t)jj * NC;
            float4 v = *reinterpret_cast<const float4*>(row + 4 * t);
            f4acc(p1a[jj], v);
            f4acc(q, v);
            s3l[jj][c4 + 0][kt] = v.x;
            s3l[jj][c4 + 1][kt] = v.y;
            s3l[jj][c4 + 2][kt] = v.z;
            s3l[jj][c4 + 3][kt] = v.w;
            if (kt == i){   // d13[b,i,j,c] = x[b,i,j,i,c]
                *reinterpret_cast<uint2*>(c_d13 + (((size_t)(b * 64 + i)) * 64 + j) * 32 + c4) = pack4(v);
            }
            if (kt == j){   // d23[b,i,j,c] = x[b,i,j,j,c]
                *reinterpret_cast<uint2*>(c_d23 + (((size_t)(b * 64 + i)) * 64 + j) * 32 + c4) = pack4(v);
            }
            if (i == j){    // d12[b,i,k,c] = x[b,i,i,k,c]; elem idx = kt*32+c4 = 4t
                *reinterpret_cast<uint2*>(c_d12 + ((size_t)(b * 64 + i)) * 2048 + 4 * (size_t)t) = pack4(v);
            }
        }
        float* o2 = p2 + ((size_t)((b * 8 + jg) * 64 + i)) * 2048;
        *reinterpret_cast<float4*>(o2 + 4 * t) = q;

        __syncthreads();
        {   // s3 reduce over kt
            const float* sp = &s3l[rjj][rc][rh * 32];
            float s = 0.f;
            #pragma unroll
            for (int g = 0; g < 32; ++g) s += sp[g];
            s += __shfl_xor(s, 32, 64);
            if (rh == 0){
                c_s3[(((size_t)(b * 64 + i)) * 64 + jg * 8 + rjj) * 32 + rc] = bf16b(s * (1.f/64.f));
            }
        }
        __syncthreads();
    }
    #pragma unroll
    for (int jj = 0; jj < 8; ++jj){
        float* o1 = p1 + ((size_t)((b * 8 + ig) * 64 + jg * 8 + jj)) * 2048;
        *reinterpret_cast<float4*>(o1 + 4 * t) = p1a[jj];
    }
}

// ---------------------------------------------------------------------------
// K2: reduce 8 partials -> s1/s2 comps (bf16 means). 512 blocks.
__global__ __launch_bounds__(256) void k_reduce(
    const float* __restrict__ p1, const float* __restrict__ p2,
    u16* __restrict__ c_s1, u16* __restrict__ c_s2)
{
    int blk = blockIdx.x;                 // b*64 + sx*32 + ch
    int b = blk >> 6, sx = (blk >> 5) & 1, ch = blk & 31;
    const float* P = sx ? p2 : p1;
    u16* O = sx ? c_s2 : c_s1;
    int t = threadIdx.x;
    #pragma unroll
    for (int r2 = 0; r2 < 2; ++r2){
        int row = ch * 2 + r2;
        float4 a0v = make_float4(0,0,0,0), a1v = make_float4(0,0,0,0);
        #pragma unroll
        for (int g = 0; g < 8; ++g){
            const float* src = P + ((size_t)((b * 8 + g) * 64 + row)) * 2048;
            f4acc(a0v, *reinterpret_cast<const float4*>(src + 4 * t));
            f4acc(a1v, *reinterpret_cast<const float4*>(src + 1024 + 4 * t));
        }
        u16* ob = O + ((size_t)(b * 64 + row)) * 2048;
        *reinterpret_cast<uint2*>(ob + 4 * t)        = pack4s(a0v, 1.f/64.f);
        *reinterpret_cast<uint2*>(ob + 1024 + 4 * t) = pack4s(a1v, 1.f/64.f);
    }
}

// ---------------------------------------------------------------------------
// K3: a1 [B][64][320], a0 [B][160] from bf16 comps. Block=(b, m, pchunk16).
__global__ __launch_bounds__(256) void k_a1a0(
    const u16* __restrict__ comps,
    float* __restrict__ a1, float* __restrict__ a0)
{
    int blk = blockIdx.x;                 // 160: (b*5+m)*4 + pc
    int pc = blk & 3, m = (blk >> 2) % 5, b = blk / 20;
    const int cidx [5] = {0, 1, 3, 4, 5};
    const int rowch[5] = {1, 2, 4, 6, 8};
    const int colch[5] = {0, -1, 3, 5, 7};
    const int a0i  [5] = {0, -1, 1, 2, 3};

    const u16* M = comps + (size_t)cidx[m] * CMPE + (size_t)b * NNC;
    int t = threadIdx.x, c = t & 31, qb = (t >> 5) * 8;
    int p0 = pc * 16;
    float colacc[8] = {0,0,0,0,0,0,0,0};
    __shared__ float red[2048];
    __shared__ float rowc[16][32];
    for (int pp0 = 0; pp0 < 16; pp0 += 8){
        #pragma unroll
        for (int pp = 0; pp < 8; ++pp){
            const u16* row = M + (size_t)(p0 + pp0 + pp) * 2048;
            float part = 0.f;
            #pragma unroll
            for (int kk = 0; kk < 8; ++kk){
                float v = b2f(row[(qb + kk) * 32 + c]);
                colacc[kk] += v; part += v;
            }
            red[pp * 256 + t] = part;
        }
        __syncthreads();
        {
            int pp = t >> 5, cc = t & 31;
            float ssum = 0.f;
            #pragma unroll
            for (int g = 0; g < 8; ++g) ssum += red[pp * 256 + g * 32 + cc];
            rowc[pp0 + pp][cc] = ssum;
            a1[((size_t)b * 64 + p0 + pp0 + pp) * 320 + rowch[m] * 32 + cc] = ssum * (1.f/64.f);
        }
        __syncthreads();
    }
    if (colch[m] >= 0){
        #pragma unroll
        for (int kk = 0; kk < 8; ++kk)
            atomicAdd(&a1[((size_t)b * 64 + qb + kk) * 320 + colch[m] * 32 + c],
                      colacc[kk] * (1.f/64.f));
    }
    if (a0i[m] >= 0 && t < 32){
        float tot = 0.f;
        #pragma unroll
        for (int r = 0; r < 16; ++r) tot += rowc[r][t];
        atomicAdd(&a0[(size_t)b * 160 + a0i[m] * 32 + t], tot * (1.f/4096.f));
    }
    if (m == 2){                          // d12 triple-diag -> chunk9 + a0[4]
        #pragma unroll
        for (int r = 0; r < 2; ++r){
            int idx = t + r * 256;        // 0..511
            int pl = idx >> 5, cc = idx & 31;
            int p = p0 + pl;
            float dv = b2f(M[((size_t)p * 64 + p) * 32 + cc]);
            a1[((size_t)b * 64 + p) * 320 + 288 + cc] = dv;
            atomicAdd(&a0[(size_t)b * 160 + 128 + cc], dv * (1.f/64.f));
        }
    }
}

// ---------------------------------------------------------------------------
// K4: u1p/u1t/fov vectors from a1,a0.
__global__ __launch_bounds__(256) void k_uvec(
    const float* __restrict__ a1, const float* __restrict__ a0,
    float* __restrict__ u1p, float* __restrict__ u1t, float* __restrict__ fov,
    const float* __restrict__ W12,  const float* __restrict__ b12,
    const float* __restrict__ W12t, const float* __restrict__ b12t,
    const float* __restrict__ W02,  const float* __restrict__ b02,
    const float* __restrict__ W11,  const float* __restrict__ b11,
    const float* __restrict__ W01,  const float* __restrict__ b01,
    const float* __restrict__ b22)
{
    int b = blockIdx.x >> 3, pg = blockIdx.x & 7;   // 64 blocks
    int t = threadIdx.x;
    int p = pg * 8 + (t >> 5), o = t & 31;
    const float* a1r = a1 + ((size_t)b * 64 + p) * 320;
    const float* a0r = a0 + (size_t)b * 160;
    float accP = b12[o] + b02[o] + b22[o];
    float accT = b12t[o];
    float accF = b11[o] + b01[o];
    for (int f = 0; f < 320; ++f){
        float a = a1r[f];
        accP = fmaf(a, W12 [f * 32 + o], accP);
        accT = fmaf(a, W12t[f * 32 + o], accT);
        accF = fmaf(a, W11 [f * 32 + o], accF);
    }
    for (int g = 0; g < 160; ++g){
        float a = a0r[g];
        accP = fmaf(a, W02[g * 32 + o], accP);
        accF = fmaf(a, W01[g * 32 + o], accF);
    }
    size_t idx = ((size_t)b * 64 + p) * 32 + o;
    u1p[idx] = accP; u1t[idx] = accT; fov[idx] = accF;
}

// ---------------------------------------------------------------------------
// K5: out[b,p,q,o] = A[q,f]@W22[f,o] + B[q,f]@W22[192+f,o] + u1p[b,p,o]
//                    + u1t[b,q,o] + (p==q)*fov[b,p,o]
__global__ __launch_bounds__(256, 2) void k_out(
    const u16* __restrict__ comps, const float* __restrict__ W22,
    const float* __restrict__ u1p, const float* __restrict__ u1t,
    const float* __restrict__ fov, float* __restrict__ out)
{
    __shared__ __align__(16) u16 Ast[192 * 68];   // [f][q], pad 68
    __shared__ __align__(16) u16 Bst[192 * 68];
    __shared__ __align__(16) u16 Wls[192 * 32];   // [f][o]
    int blk = blockIdx.x;                 // b*64+p
    int b = blk >> 6, p = blk & 63;
    int t = threadIdx.x;
    int q = t >> 2, c8 = (t & 3) * 8;

    #pragma unroll
    for (int t6 = 0; t6 < 6; ++t6){
        const u16* cmp = comps + (size_t)t6 * CMPE + (size_t)b * NNC;
        uint4 av = *reinterpret_cast<const uint4*>(cmp + (size_t)p * 2048 + q * 32 + c8);
        uint4 bv = *reinterpret_cast<const uint4*>(cmp + (size_t)q * 2048 + p * 32 + c8);
        int fb = t6 * 32 + c8;
        Ast[(fb+0)*68 + q] = (u16)av.x; Ast[(fb+1)*68 + q] = (u16)(av.x >> 16);
        Ast[(fb+2)*68 + q] = (u16)av.y; Ast[(fb+3)*68 + q] = (u16)(av.y >> 16);
        Ast[(fb+4)*68 + q] = (u16)av.z; Ast[(fb+5)*68 + q] = (u16)(av.z >> 16);
        Ast[(fb+6)*68 + q] = (u16)av.w; Ast[(fb+7)*68 + q] = (u16)(av.w >> 16);
        Bst[(fb+0)*68 + q] = (u16)bv.x; Bst[(fb+1)*68 + q] = (u16)(bv.x >> 16);
        Bst[(fb+2)*68 + q] = (u16)bv.y; Bst[(fb+3)*68 + q] = (u16)(bv.y >> 16);
        Bst[(fb+4)*68 + q] = (u16)bv.z; Bst[(fb+5)*68 + q] = (u16)(bv.z >> 16);
        Bst[(fb+6)*68 + q] = (u16)bv.w; Bst[(fb+7)*68 + q] = (u16)(bv.w >> 16);
    }
    #pragma unroll
    for (int r = 0; r < 6; ++r){          // W half 0
        int idx = t + r * 256;
        int f = idx >> 3, o4 = (idx & 7) * 4;
        float4 w = *reinterpret_cast<const float4*>(W22 + (size_t)idx * 4);
        Wls[f*32 + o4 + 0] = bf16b(w.x); Wls[f*32 + o4 + 1] = bf16b(w.y);
        Wls[f*32 + o4 + 2] = bf16b(w.z); Wls[f*32 + o4 + 3] = bf16b(w.w);
    }
    __syncthreads();

    int qi = t & 15, oi = t >> 4;
    int q0 = qi * 4, o0 = oi * 2;
    float acc00=0,acc01=0,acc10=0,acc11=0,acc20=0,acc21=0,acc30=0,acc31=0;

    #pragma unroll 8
    for (int f = 0; f < 192; ++f){
        uint2 a4 = *reinterpret_cast<const uint2*>(Ast + f * 68 + q0);
        unsigned wp = *reinterpret_cast<const unsigned*>(Wls + f * 32 + o0);
        float w0v = lo16(wp), w1v = hi16(wp);
        float A0v = lo16(a4.x), A1v = hi16(a4.x), A2v = lo16(a4.y), A3v = hi16(a4.y);
        acc00 = fmaf(A0v, w0v, acc00); acc01 = fmaf(A0v, w1v, acc01);
        acc10 = fmaf(A1v, w0v, acc10); acc11 = fmaf(A1v, w1v, acc11);
        acc20 = fmaf(A2v, w0v, acc20); acc21 = fmaf(A2v, w1v, acc21);
        acc30 = fmaf(A3v, w0v, acc30); acc31 = fmaf(A3v, w1v, acc31);
    }
    __syncthreads();
    #pragma unroll
    for (int r = 0; r < 6; ++r){          // W half 1
        int idx = t + r * 256;
        int f = idx >> 3, o4 = (idx & 7) * 4;
        float4 w = *reinterpret_cast<const float4*>(W22 + 6144 + (size_t)idx * 4);
        Wls[f*32 + o4 + 0] = bf16b(w.x); Wls[f*32 + o4 + 1] = bf16b(w.y);
        Wls[f*32 + o4 + 2] = bf16b(w.z); Wls[f*32 + o4 + 3] = bf16b(w.w);
    }
    __syncthreads();
    #pragma unroll 8
    for (int f = 0; f < 192; ++f){
        uint2 a4 = *reinterpret_cast<const uint2*>(Bst + f * 68 + q0);
        unsigned wp = *reinterpret_cast<const unsigned*>(Wls + f * 32 + o0);
        float w0v = lo16(wp), w1v = hi16(wp);
        float A0v = lo16(a4.x), A1v = hi16(a4.x), A2v = lo16(a4.y), A3v = hi16(a4.y);
        acc00 = fmaf(A0v, w0v, acc00); acc01 = fmaf(A0v, w1v, acc01);
        acc10 = fmaf(A1v, w0v, acc10); acc11 = fmaf(A1v, w1v, acc11);
        acc20 = fmaf(A2v, w0v, acc20); acc21 = fmaf(A2v, w1v, acc21);
        acc30 = fmaf(A3v, w0v, acc30); acc31 = fmaf(A3v, w1v, acc31);
    }

    size_t ub = ((size_t)b * 64 + p) * 32;
    float up0 = u1p[ub + o0], up1 = u1p[ub + o0 + 1];
    const float* fovp = fov + ub;
    float accs[4][2] = {{acc00,acc01},{acc10,acc11},{acc20,acc21},{acc30,acc31}};
    #pragma unroll
    for (int iq = 0; iq < 4; ++iq){
        int qq = q0 + iq;
        size_t tb = ((size_t)b * 64 + qq) * 32;
        float e0 = up0 + u1t[tb + o0];
        float e1 = up1 + u1t[tb + o0 + 1];
        if (qq == p){ e0 += fovp[o0]; e1 += fovp[o0 + 1]; }
        float2 v; v.x = accs[iq][0] + e0; v.y = accs[iq][1] + e1;
        *reinterpret_cast<float2*>(out + (((size_t)b * 64 + p) * 64 + qq) * 32 + o0) = v;
    }
}

// ---------------------------------------------------------------------------
extern "C" void kernel_launch(void* const* d_in, const int* in_sizes, int n_in,
                              void* d_out, int out_size, void* d_ws, size_t ws_size,
                              hipStream_t stream){
    const float* x    = (const float*)d_in[0];
    const float* W22  = (const float*)d_in[1];
    const float* b22  = (const float*)d_in[2];
    const float* W12  = (const float*)d_in[3];
    const float* b12  = (const float*)d_in[4];
    const float* W12t = (const float*)d_in[5];
    const float* b12t = (const float*)d_in[6];
    const float* W02  = (const float*)d_in[7];
    const float* b02  = (const float*)d_in[8];
    const float* W11  = (const float*)d_in[9];
    const float* b11  = (const float*)d_in[10];
    const float* W01  = (const float*)d_in[11];
    const float* b01  = (const float*)d_in[12];
    float* out = (float*)d_out;
    float* ws  = (float*)d_ws;

    // ws layout (float offsets) — p1/p2 are [B][8][64][2048] = 8,388,608 floats EACH
    float* p1   = ws;                        // [0, 8388608)
    float* p2   = ws + 8388608;              // [8388608, 16777216)
    u16*  comps = (u16*)(ws + 16777216);     // 6*CMPE u16 = 3,145,728 float-slots
    float* a1   = ws + 19922944;             // 163,840 f
    float* a0   = ws + 20086784;             // 1,280 f
    float* u1p  = ws + 20088064;             // 16,384 f
    float* u1t  = ws + 20104448;             // 16,384 f
    float* fovv = ws + 20120832;             // 16,384 f

    hipMemsetAsync(a1, 0, (163840 + 1280) * sizeof(float), stream);
    k_pass1 <<<512, 512, 0, stream>>>(x, p1, p2,
                comps + 2*(size_t)CMPE, comps + 3*(size_t)CMPE,
                comps + 4*(size_t)CMPE, comps + 5*(size_t)CMPE);
    k_reduce<<<512, 256, 0, stream>>>(p1, p2, comps, comps + (size_t)CMPE);
    k_a1a0  <<<160, 256, 0, stream>>>(comps, a1, a0);
    k_uvec  <<<64,  256, 0, stream>>>(a1, a0, u1p, u1t, fovv,
                W12, b12, W12t, b12t, W02, b02, W11, b11, W01, b01, b22);
    k_out   <<<512, 256, 0, stream>>>(comps, W22, u1p, u1t, fovv, out);
}

// Round 6
// 131.075 us; speedup vs baseline: 1.9430x; 1.1936x over previous
//
#include <hip/hip_runtime.h>
#include <hip/hip_bf16.h>
#include <stdint.h>

// B=8, n=64, C=32, O=32
#define NC   2048      // n*C
#define NNC  131072    // n*n*C
#define N3C  8388608   // n*n*n*C per batch
#define CMPE 1048576   // per-comp elements (B*n*n*C)

typedef unsigned short u16;

__device__ __forceinline__ u16 bf16b(float x){
    unsigned u = __float_as_uint(x);
    u += 0x7FFFu + ((u >> 16) & 1u);      // RNE
    return (u16)(u >> 16);
}
__device__ __forceinline__ float b2f(u16 h){ return __uint_as_float(((unsigned)h) << 16); }
__device__ __forceinline__ float lo16(unsigned u){ return __uint_as_float(u << 16); }
__device__ __forceinline__ float hi16(unsigned u){ return __uint_as_float(u & 0xFFFF0000u); }
__device__ __forceinline__ void f4acc(float4& a, const float4 b){
    a.x += b.x; a.y += b.y; a.z += b.z; a.w += b.w;
}
__device__ __forceinline__ void addp4(float4& a, const uint2 u){
    a.x += lo16(u.x); a.y += hi16(u.x); a.z += lo16(u.y); a.w += hi16(u.y);
}
__device__ __forceinline__ uint2 pack4(float4 v){
    uint2 r;
    r.x = (unsigned)bf16b(v.x) | ((unsigned)bf16b(v.y) << 16);
    r.y = (unsigned)bf16b(v.z) | ((unsigned)bf16b(v.w) << 16);
    return r;
}
__device__ __forceinline__ uint2 pack4s(float4 v, float s){
    v.x *= s; v.y *= s; v.z *= s; v.w *= s;
    return pack4(v);
}

// ---------------------------------------------------------------------------
// K1: single pass over x. Block=(b, ig, jg), 512 threads: thread=(k, c4).
// Software-pipelined: next ii's loads are issued before the LDS-only s3
// reduce so HBM stays busy. p1/p2 partials written as packed bf16.
__global__ __launch_bounds__(512, 2) void k_pass1(
    const float* __restrict__ x,
    u16* __restrict__ p1, u16* __restrict__ p2,
    u16* __restrict__ c_s3, u16* __restrict__ c_d12,
    u16* __restrict__ c_d13, u16* __restrict__ c_d23)
{
    int blk = blockIdx.x;                 // (b*8+ig)*8+jg
    int jg = blk & 7, ig = (blk >> 3) & 7, b = blk >> 6;
    int t = threadIdx.x;                  // 0..511
    int kt = t >> 3, c4 = (t & 7) * 4;    // k 0..63, c4 in {0,4,...,28}

    __shared__ float s3l[8][32][65];      // [jj][c][kt pad65]  66.6 KB

    float4 p1a[8];
    #pragma unroll
    for (int a = 0; a < 8; ++a) p1a[a] = make_float4(0,0,0,0);

    const float* xb = x + (size_t)b * N3C + (size_t)ig * 8 * NNC + (size_t)jg * 8 * NC;

    int rjj = t >> 6, rh = (t >> 5) & 1, rc = t & 31;   // reduce mapping

    float4 v[8];
    #pragma unroll
    for (int jj = 0; jj < 8; ++jj)
        v[jj] = *reinterpret_cast<const float4*>(xb + (size_t)jj * NC + 4 * t);

    for (int ii = 0; ii < 8; ++ii){
        int i = ig * 8 + ii;
        float4 q = make_float4(0,0,0,0);
        #pragma unroll
        for (int jj = 0; jj < 8; ++jj){
            int j = jg * 8 + jj;
            f4acc(p1a[jj], v[jj]);
            f4acc(q, v[jj]);
            s3l[jj][c4 + 0][kt] = v[jj].x;
            s3l[jj][c4 + 1][kt] = v[jj].y;
            s3l[jj][c4 + 2][kt] = v[jj].z;
            s3l[jj][c4 + 3][kt] = v[jj].w;
            if (kt == i){   // d13[b,i,j,c] = x[b,i,j,i,c]
                *reinterpret_cast<uint2*>(c_d13 + (((size_t)(b * 64 + i)) * 64 + j) * 32 + c4) = pack4(v[jj]);
            }
            if (kt == j){   // d23[b,i,j,c] = x[b,i,j,j,c]
                *reinterpret_cast<uint2*>(c_d23 + (((size_t)(b * 64 + i)) * 64 + j) * 32 + c4) = pack4(v[jj]);
            }
            if (i == j){    // d12[b,i,k,c] = x[b,i,i,k,c]; elem idx = 4t
                *reinterpret_cast<uint2*>(c_d12 + ((size_t)(b * 64 + i)) * 2048 + 4 * (size_t)t) = pack4(v[jj]);
            }
        }
        // p2 row (partial sum over this jg), bf16
        *reinterpret_cast<uint2*>(p2 + ((size_t)((b * 8 + jg) * 64 + i)) * 2048 + 4 * (size_t)t) = pack4(q);

        __syncthreads();
        // prefetch next ii while the LDS reduce runs
        float4 vn[8];
        if (ii < 7){
            #pragma unroll
            for (int jj = 0; jj < 8; ++jj)
                vn[jj] = *reinterpret_cast<const float4*>(xb + (size_t)(ii + 1) * NNC + (size_t)jj * NC + 4 * t);
        }
        {   // s3 reduce over kt (LDS only)
            const float* sp = &s3l[rjj][rc][rh * 32];
            float s = 0.f;
            #pragma unroll
            for (int g = 0; g < 32; ++g) s += sp[g];
            s += __shfl_xor(s, 32, 64);
            if (rh == 0){
                c_s3[(((size_t)(b * 64 + i)) * 64 + jg * 8 + rjj) * 32 + rc] = bf16b(s * (1.f/64.f));
            }
        }
        __syncthreads();
        if (ii < 7){
            #pragma unroll
            for (int jj = 0; jj < 8; ++jj) v[jj] = vn[jj];
        }
    }
    #pragma unroll
    for (int jj = 0; jj < 8; ++jj){
        u16* o1 = p1 + ((size_t)((b * 8 + ig) * 64 + jg * 8 + jj)) * 2048;
        *reinterpret_cast<uint2*>(o1 + 4 * (size_t)t) = pack4(p1a[jj]);
    }
}

// ---------------------------------------------------------------------------
// K2: reduce 8 bf16 partials -> s1/s2 comps (bf16 means). 512 blocks.
__global__ __launch_bounds__(256) void k_reduce(
    const u16* __restrict__ p1, const u16* __restrict__ p2,
    u16* __restrict__ c_s1, u16* __restrict__ c_s2)
{
    int blk = blockIdx.x;                 // b*64 + sx*32 + ch
    int b = blk >> 6, sx = (blk >> 5) & 1, ch = blk & 31;
    const u16* P = sx ? p2 : p1;
    u16* O = sx ? c_s2 : c_s1;
    int t = threadIdx.x;
    #pragma unroll
    for (int r2 = 0; r2 < 2; ++r2){
        int row = ch * 2 + r2;
        float4 a0v = make_float4(0,0,0,0), a1v = make_float4(0,0,0,0);
        #pragma unroll
        for (int g = 0; g < 8; ++g){
            const u16* src = P + ((size_t)((b * 8 + g) * 64 + row)) * 2048;
            addp4(a0v, *reinterpret_cast<const uint2*>(src + 4 * t));
            addp4(a1v, *reinterpret_cast<const uint2*>(src + 1024 + 4 * t));
        }
        u16* ob = O + ((size_t)(b * 64 + row)) * 2048;
        *reinterpret_cast<uint2*>(ob + 4 * t)        = pack4s(a0v, 1.f/64.f);
        *reinterpret_cast<uint2*>(ob + 1024 + 4 * t) = pack4s(a1v, 1.f/64.f);
    }
}

// ---------------------------------------------------------------------------
// K3: a1 [B][64][320], a0 [B][160] from bf16 comps. Block=(b,m), full p-range,
// no atomics, no pre-zeroing. 40 blocks.
__global__ __launch_bounds__(256) void k_a1a0(
    const u16* __restrict__ comps,
    float* __restrict__ a1, float* __restrict__ a0)
{
    int b = blockIdx.x / 5, m = blockIdx.x % 5;
    const int cidx [5] = {0, 1, 3, 4, 5};
    const int rowch[5] = {1, 2, 4, 6, 8};
    const int colch[5] = {0, -1, 3, 5, 7};
    const int a0i  [5] = {0, -1, 1, 2, 3};

    const u16* M = comps + (size_t)cidx[m] * CMPE + (size_t)b * NNC;
    int t = threadIdx.x, c = t & 31, qb = (t >> 5) * 8;
    float colacc[8] = {0,0,0,0,0,0,0,0};
    __shared__ float red[2048];
    __shared__ float rowc[64][32];
    for (int p0 = 0; p0 < 64; p0 += 8){
        #pragma unroll
        for (int pp = 0; pp < 8; ++pp){
            const u16* row = M + (size_t)(p0 + pp) * 2048;
            float part = 0.f;
            #pragma unroll
            for (int kk = 0; kk < 8; ++kk){
                float v = b2f(row[(qb + kk) * 32 + c]);
                colacc[kk] += v; part += v;
            }
            red[pp * 256 + t] = part;
        }
        __syncthreads();
        {
            int pp = t >> 5, cc = t & 31;
            float ssum = 0.f;
            #pragma unroll
            for (int g = 0; g < 8; ++g) ssum += red[pp * 256 + g * 32 + cc];
            rowc[p0 + pp][cc] = ssum;
            a1[((size_t)b * 64 + p0 + pp) * 320 + rowch[m] * 32 + cc] = ssum * (1.f/64.f);
        }
        __syncthreads();
    }
    if (colch[m] >= 0){
        #pragma unroll
        for (int kk = 0; kk < 8; ++kk)
            a1[((size_t)b * 64 + qb + kk) * 320 + colch[m] * 32 + c] = colacc[kk] * (1.f/64.f);
    }
    if (a0i[m] >= 0){
        int pg = t >> 5;
        float tp = 0.f;
        #pragma unroll
        for (int r = 0; r < 8; ++r) tp += rowc[pg * 8 + r][c];
        red[t] = tp;
        __syncthreads();
        if (t < 32){
            float tot = 0.f;
            #pragma unroll
            for (int g = 0; g < 8; ++g) tot += red[g * 32 + t];
            a0[(size_t)b * 160 + a0i[m] * 32 + t] = tot * (1.f/4096.f);
        }
    }
    if (m == 2){                          // d12 triple-diag -> chunk9 + a0[4]
        __syncthreads();
        float dp = 0.f;
        #pragma unroll
        for (int r = 0; r < 8; ++r){
            int p = (t >> 5) + 8 * r;
            float dv = b2f(M[((size_t)p * 64 + p) * 32 + c]);
            a1[((size_t)b * 64 + p) * 320 + 288 + c] = dv;
            dp += dv;
        }
        red[t] = dp;
        __syncthreads();
        if (t < 32){
            float s = 0.f;
            #pragma unroll
            for (int g = 0; g < 8; ++g) s += red[g * 32 + t];
            a0[(size_t)b * 160 + 128 + t] = s * (1.f/64.f);
        }
    }
}

// ---------------------------------------------------------------------------
// K4: u1p/u1t/fov vectors from a1,a0.
__global__ __launch_bounds__(256) void k_uvec(
    const float* __restrict__ a1, const float* __restrict__ a0,
    float* __restrict__ u1p, float* __restrict__ u1t, float* __restrict__ fov,
    const float* __restrict__ W12,  const float* __restrict__ b12,
    const float* __restrict__ W12t, const float* __restrict__ b12t,
    const float* __restrict__ W02,  const float* __restrict__ b02,
    const float* __restrict__ W11,  const float* __restrict__ b11,
    const float* __restrict__ W01,  const float* __restrict__ b01,
    const float* __restrict__ b22)
{
    int b = blockIdx.x >> 3, pg = blockIdx.x & 7;   // 64 blocks
    int t = threadIdx.x;
    int p = pg * 8 + (t >> 5), o = t & 31;
    const float* a1r = a1 + ((size_t)b * 64 + p) * 320;
    const float* a0r = a0 + (size_t)b * 160;
    float accP = b12[o] + b02[o] + b22[o];
    float accT = b12t[o];
    float accF = b11[o] + b01[o];
    for (int f = 0; f < 320; ++f){
        float a = a1r[f];
        accP = fmaf(a, W12 [f * 32 + o], accP);
        accT = fmaf(a, W12t[f * 32 + o], accT);
        accF = fmaf(a, W11 [f * 32 + o], accF);
    }
    for (int g = 0; g < 160; ++g){
        float a = a0r[g];
        accP = fmaf(a, W02[g * 32 + o], accP);
        accF = fmaf(a, W01[g * 32 + o], accF);
    }
    size_t idx = ((size_t)b * 64 + p) * 32 + o;
    u1p[idx] = accP; u1t[idx] = accT; fov[idx] = accF;
}

// ---------------------------------------------------------------------------
// K5: out[b,p,q,o] = A[q,f]@W22[f,o] + B[q,f]@W22[192+f,o] + u1p[b,p,o]
//                    + u1t[b,q,o] + (p==q)*fov[b,p,o]
__global__ __launch_bounds__(256, 2) void k_out(
    const u16* __restrict__ comps, const float* __restrict__ W22,
    const float* __restrict__ u1p, const float* __restrict__ u1t,
    const float* __restrict__ fov, float* __restrict__ out)
{
    __shared__ __align__(16) u16 Ast[192 * 68];   // [f][q], pad 68
    __shared__ __align__(16) u16 Bst[192 * 68];
    __shared__ __align__(16) u16 Wls[192 * 32];   // [f][o]
    int blk = blockIdx.x;                 // b*64+p
    int b = blk >> 6, p = blk & 63;
    int t = threadIdx.x;
    int q = t >> 2, c8 = (t & 3) * 8;

    #pragma unroll
    for (int t6 = 0; t6 < 6; ++t6){
        const u16* cmp = comps + (size_t)t6 * CMPE + (size_t)b * NNC;
        uint4 av = *reinterpret_cast<const uint4*>(cmp + (size_t)p * 2048 + q * 32 + c8);
        uint4 bv = *reinterpret_cast<const uint4*>(cmp + (size_t)q * 2048 + p * 32 + c8);
        int fb = t6 * 32 + c8;
        Ast[(fb+0)*68 + q] = (u16)av.x; Ast[(fb+1)*68 + q] = (u16)(av.x >> 16);
        Ast[(fb+2)*68 + q] = (u16)av.y; Ast[(fb+3)*68 + q] = (u16)(av.y >> 16);
        Ast[(fb+4)*68 + q] = (u16)av.z; Ast[(fb+5)*68 + q] = (u16)(av.z >> 16);
        Ast[(fb+6)*68 + q] = (u16)av.w; Ast[(fb+7)*68 + q] = (u16)(av.w >> 16);
        Bst[(fb+0)*68 + q] = (u16)bv.x; Bst[(fb+1)*68 + q] = (u16)(bv.x >> 16);
        Bst[(fb+2)*68 + q] = (u16)bv.y; Bst[(fb+3)*68 + q] = (u16)(bv.y >> 16);
        Bst[(fb+4)*68 + q] = (u16)bv.z; Bst[(fb+5)*68 + q] = (u16)(bv.z >> 16);
        Bst[(fb+6)*68 + q] = (u16)bv.w; Bst[(fb+7)*68 + q] = (u16)(bv.w >> 16);
    }
    #pragma unroll
    for (int r = 0; r < 6; ++r){          // W half 0
        int idx = t + r * 256;
        int f = idx >> 3, o4 = (idx & 7) * 4;
        float4 w = *reinterpret_cast<const float4*>(W22 + (size_t)idx * 4);
        Wls[f*32 + o4 + 0] = bf16b(w.x); Wls[f*32 + o4 + 1] = bf16b(w.y);
        Wls[f*32 + o4 + 2] = bf16b(w.z); Wls[f*32 + o4 + 3] = bf16b(w.w);
    }
    __syncthreads();

    int qi = t & 15, oi = t >> 4;
    int q0 = qi * 4, o0 = oi * 2;
    float acc00=0,acc01=0,acc10=0,acc11=0,acc20=0,acc21=0,acc30=0,acc31=0;

    #pragma unroll 8
    for (int f = 0; f < 192; ++f){
        uint2 a4 = *reinterpret_cast<const uint2*>(Ast + f * 68 + q0);
        unsigned wp = *reinterpret_cast<const unsigned*>(Wls + f * 32 + o0);
        float w0v = lo16(wp), w1v = hi16(wp);
        float A0v = lo16(a4.x), A1v = hi16(a4.x), A2v = lo16(a4.y), A3v = hi16(a4.y);
        acc00 = fmaf(A0v, w0v, acc00); acc01 = fmaf(A0v, w1v, acc01);
        acc10 = fmaf(A1v, w0v, acc10); acc11 = fmaf(A1v, w1v, acc11);
        acc20 = fmaf(A2v, w0v, acc20); acc21 = fmaf(A2v, w1v, acc21);
        acc30 = fmaf(A3v, w0v, acc30); acc31 = fmaf(A3v, w1v, acc31);
    }
    __syncthreads();
    #pragma unroll
    for (int r = 0; r < 6; ++r){          // W half 1
        int idx = t + r * 256;
        int f = idx >> 3, o4 = (idx & 7) * 4;
        float4 w = *reinterpret_cast<const float4*>(W22 + 6144 + (size_t)idx * 4);
        Wls[f*32 + o4 + 0] = bf16b(w.x); Wls[f*32 + o4 + 1] = bf16b(w.y);
        Wls[f*32 + o4 + 2] = bf16b(w.z); Wls[f*32 + o4 + 3] = bf16b(w.w);
    }
    __syncthreads();
    #pragma unroll 8
    for (int f = 0; f < 192; ++f){
        uint2 a4 = *reinterpret_cast<const uint2*>(Bst + f * 68 + q0);
        unsigned wp = *reinterpret_cast<const unsigned*>(Wls + f * 32 + o0);
        float w0v = lo16(wp), w1v = hi16(wp);
        float A0v = lo16(a4.x), A1v = hi16(a4.x), A2v = lo16(a4.y), A3v = hi16(a4.y);
        acc00 = fmaf(A0v, w0v, acc00); acc01 = fmaf(A0v, w1v, acc01);
        acc10 = fmaf(A1v, w0v, acc10); acc11 = fmaf(A1v, w1v, acc11);
        acc20 = fmaf(A2v, w0v, acc20); acc21 = fmaf(A2v, w1v, acc21);
        acc30 = fmaf(A3v, w0v, acc30); acc31 = fmaf(A3v, w1v, acc31);
    }

    size_t ub = ((size_t)b * 64 + p) * 32;
    float up0 = u1p[ub + o0], up1 = u1p[ub + o0 + 1];
    const float* fovp = fov + ub;
    float accs[4][2] = {{acc00,acc01},{acc10,acc11},{acc20,acc21},{acc30,acc31}};
    #pragma unroll
    for (int iq = 0; iq < 4; ++iq){
        int qq = q0 + iq;
        size_t tb = ((size_t)b * 64 + qq) * 32;
        float e0 = up0 + u1t[tb + o0];
        float e1 = up1 + u1t[tb + o0 + 1];
        if (qq == p){ e0 += fovp[o0]; e1 += fovp[o0 + 1]; }
        float2 v; v.x = accs[iq][0] + e0; v.y = accs[iq][1] + e1;
        *reinterpret_cast<float2*>(out + (((size_t)b * 64 + p) * 64 + qq) * 32 + o0) = v;
    }
}

// ---------------------------------------------------------------------------
extern "C" void kernel_launch(void* const* d_in, const int* in_sizes, int n_in,
                              void* d_out, int out_size, void* d_ws, size_t ws_size,
                              hipStream_t stream){
    const float* x    = (const float*)d_in[0];
    const float* W22  = (const float*)d_in[1];
    const float* b22  = (const float*)d_in[2];
    const float* W12  = (const float*)d_in[3];
    const float* b12  = (const float*)d_in[4];
    const float* W12t = (const float*)d_in[5];
    const float* b12t = (const float*)d_in[6];
    const float* W02  = (const float*)d_in[7];
    const float* b02  = (const float*)d_in[8];
    const float* W11  = (const float*)d_in[9];
    const float* b11  = (const float*)d_in[10];
    const float* W01  = (const float*)d_in[11];
    const float* b01  = (const float*)d_in[12];
    float* out = (float*)d_out;
    float* ws  = (float*)d_ws;

    // ws layout (float-slot offsets):
    // p1: u16[8388608] -> 4,194,304 float-slots    [0, 4194304)
    // p2: u16[8388608]                             [4194304, 8388608)
    // comps: u16[6*CMPE] -> 3,145,728 float-slots  [8388608, 11534336)
    u16*  p1    = (u16*)ws;
    u16*  p2    = (u16*)(ws + 4194304);
    u16*  comps = (u16*)(ws + 8388608);
    float* a1   = ws + 11534336;             // 163,840 f
    float* a0   = ws + 11698176;             // 1,280 f
    float* u1p  = ws + 11699456;             // 16,384 f
    float* u1t  = ws + 11715840;             // 16,384 f
    float* fovv = ws + 11732224;             // 16,384 f

    k_pass1 <<<512, 512, 0, stream>>>(x, p1, p2,
                comps + 2*(size_t)CMPE, comps + 3*(size_t)CMPE,
                comps + 4*(size_t)CMPE, comps + 5*(size_t)CMPE);
    k_reduce<<<512, 256, 0, stream>>>(p1, p2, comps, comps + (size_t)CMPE);
    k_a1a0  <<<40,  256, 0, stream>>>(comps, a1, a0);
    k_uvec  <<<64,  256, 0, stream>>>(a1, a0, u1p, u1t, fovv,
                W12, b12, W12t, b12t, W02, b02, W11, b11, W01, b01, b22);
    k_out   <<<512, 256, 0, stream>>>(comps, W22, u1p, u1t, fovv, out);
}